// Round 9
// baseline (172.851 us; speedup 1.0000x reference)
//
#include <hip/hip_runtime.h>

#define NROWS 32768
#define DDIM  128
#define KCODES 1024
#define DECAY 0.99f
#define OMD   0.01f
#define EPS   1e-5f

typedef __attribute__((ext_vector_type(8))) short short8;
typedef __attribute__((ext_vector_type(4))) float f32x4;

// ws layout (float offsets): [cssum 1][pad 1023][en2h 1024]
#define WS_CSSUM 0
#define WS_EN2H  1024

__device__ __forceinline__ unsigned int f2bf(float f) {
  union { float f; unsigned int u; } cv; cv.f = f;
  unsigned int u = cv.u;
  return (u + 0x7fffu + ((u >> 16) & 1u)) >> 16;  // RNE
}

// ---- K1: split embed into (eh, el) bf16, MFMA B-fragment layout + exact
// norms. epack frag (nt, j): j 0-3 = eh, j 4-7 = el. 512 KB, aliased into
// out_nea. Block 0 additionally reduces sum(cs) into ws (needed by K3). ----
__global__ __launch_bounds__(256) void pack_e(const float* __restrict__ embed,
                                              ushort* __restrict__ epack,
                                              float* __restrict__ en2h,
                                              const float* __restrict__ cs,
                                              float* __restrict__ cssum) {
  __shared__ float ws4[4];
  const int tid = threadIdx.x;
  const int w = tid >> 6, lane = tid & 63;
  const int nt = blockIdx.x * 4 + w;          // 64 tiles of 16 codes
  const int m = lane & 15, q = lane >> 4;
  const int row = nt * 16 + m;
  const float* ep = embed + (size_t)row * DDIM + q * 8;
  float ss = 0.f;
  #pragma unroll
  for (int kb = 0; kb < 4; ++kb) {
    float4 v0 = *(const float4*)(ep + kb * 32);
    float4 v1 = *(const float4*)(ep + kb * 32 + 4);
    float v[8] = {v0.x, v0.y, v0.z, v0.w, v1.x, v1.y, v1.z, v1.w};
    unsigned int h[8], l[8];
    #pragma unroll
    for (int j = 0; j < 8; ++j) {
      ss += v[j] * v[j];
      h[j] = f2bf(v[j]);
      float fh = __uint_as_float(h[j] << 16);
      l[j] = f2bf(v[j] - fh);
    }
    uint4 ph, pl;
    ph.x = h[0] | (h[1] << 16); ph.y = h[2] | (h[3] << 16);
    ph.z = h[4] | (h[5] << 16); ph.w = h[6] | (h[7] << 16);
    pl.x = l[0] | (l[1] << 16); pl.y = l[2] | (l[3] << 16);
    pl.z = l[4] | (l[5] << 16); pl.w = l[6] | (l[7] << 16);
    *(uint4*)(epack + (((size_t)nt * 8 + kb) * 64 + lane) * 8)     = ph;  // eh
    *(uint4*)(epack + (((size_t)nt * 8 + kb + 4) * 64 + lane) * 8) = pl;  // el
  }
  ss += __shfl_xor(ss, 16, 64);
  ss += __shfl_xor(ss, 32, 64);
  if (q == 0) en2h[row] = 0.5f * ss;

  if (blockIdx.x == 0) {                      // reduce sum(cs) for K3
    float s = cs[tid] + cs[tid + 256] + cs[tid + 512] + cs[tid + 768];
    #pragma unroll
    for (int off = 1; off < 64; off <<= 1) s += __shfl_xor(s, off, 64);
    if (lane == 0) ws4[w] = s;
    __syncthreads();
    if (tid == 0) cssum[0] = ws4[0] + ws4[1] + ws4[2] + ws4[3];
  }
}

// ---- K2: MFMA scoring + fused quantize write.
// Champion geometry (m=2, 4 wave-quarters, barrier-free, ascending tiles)
// + TRIPLE register buffer (prefetch depth 2): each proc has ~320 cy of
// prefetched loads ahead of it, covering the ~300 cy L2 latency that the
// depth-1 double buffer only half-hid (the ~45% stall R1 showed).
// No launch_bounds min-wave arg (that register cap caused R2/R6 spills). ----
__global__ __launch_bounds__(256) void vq_mfma(
    const float* __restrict__ x, const short8* __restrict__ ep8,
    const float* __restrict__ en2h, const float* __restrict__ embed,
    float* __restrict__ out_ind, float* __restrict__ out_q) {
  __shared__ unsigned long long keys[4][32];
  __shared__ int scodes[32];
  const int tid = threadIdx.x;
  const int w = tid >> 6, lane = tid & 63;
  const int c = lane & 15, q = lane >> 4;
  const int mt0 = blockIdx.x * 2;

  // A fragments from x: 2 M-tiles x (xh 0-3, xl 4-7) = 64 VGPRs
  short8 a[2][8];
  #pragma unroll
  for (int t = 0; t < 2; ++t) {
    const float* xp = x + (size_t)((mt0 + t) * 16 + c) * DDIM + q * 8;
    #pragma unroll
    for (int kb = 0; kb < 4; ++kb) {
      float4 v0 = *(const float4*)(xp + kb * 32);
      float4 v1 = *(const float4*)(xp + kb * 32 + 4);
      float v[8] = {v0.x, v0.y, v0.z, v0.w, v1.x, v1.y, v1.z, v1.w};
      short8 hh, ll;
      #pragma unroll
      for (int j = 0; j < 8; ++j) {
        unsigned int hv = f2bf(v[j]);
        hh[j] = (short)hv;
        float fh = __uint_as_float(hv << 16);
        ll[j] = (short)f2bf(v[j] - fh);
      }
      a[t][kb] = hh;
      a[t][kb + 4] = ll;
    }
  }

  float bestv[8]; int besti[8];
  #pragma unroll
  for (int i = 0; i < 8; ++i) { bestv[i] = -3.4e38f; besti[i] = 0; }

  const int nt0 = w * 16;

  // stage one 16-code tile (8 x dwordx4 + norm), ascending order
  auto stage = [&](short8 (&st)[8], float& nh, int i) {
    const short8* p = ep8 + (size_t)(nt0 + i) * 512 + lane;
    #pragma unroll
    for (int j = 0; j < 8; ++j) st[j] = p[j * 64];
    nh = en2h[(nt0 + i) * 16 + c];
  };

  // process one code tile: 24 MFMAs (K=384 compensated) + best update
  auto proc = [&](const short8 (&st)[8], float nh, int i) {
    f32x4 acc0 = {-nh, -nh, -nh, -nh};        // -0.5||e||^2 folded into init
    f32x4 acc1 = acc0;
    __builtin_amdgcn_s_setprio(1);
    #pragma unroll
    for (int kb = 0; kb < 4; ++kb) {          // xh . eh
      acc0 = __builtin_amdgcn_mfma_f32_16x16x32_bf16(a[0][kb], st[kb], acc0, 0, 0, 0);
      acc1 = __builtin_amdgcn_mfma_f32_16x16x32_bf16(a[1][kb], st[kb], acc1, 0, 0, 0);
    }
    #pragma unroll
    for (int kb = 0; kb < 4; ++kb) {          // xl . eh
      acc0 = __builtin_amdgcn_mfma_f32_16x16x32_bf16(a[0][kb + 4], st[kb], acc0, 0, 0, 0);
      acc1 = __builtin_amdgcn_mfma_f32_16x16x32_bf16(a[1][kb + 4], st[kb], acc1, 0, 0, 0);
    }
    #pragma unroll
    for (int kb = 0; kb < 4; ++kb) {          // xh . el
      acc0 = __builtin_amdgcn_mfma_f32_16x16x32_bf16(a[0][kb], st[kb + 4], acc0, 0, 0, 0);
      acc1 = __builtin_amdgcn_mfma_f32_16x16x32_bf16(a[1][kb], st[kb + 4], acc1, 0, 0, 0);
    }
    __builtin_amdgcn_s_setprio(0);
    const int code = (nt0 + i) * 16 + c;
    #pragma unroll
    for (int r = 0; r < 4; ++r) {             // C/D: col=lane&15, row=q*4+r
      if (acc0[r] > bestv[r])     { bestv[r] = acc0[r];     besti[r] = code; }
      if (acc1[r] > bestv[4 + r]) { bestv[4 + r] = acc1[r]; besti[4 + r] = code; }
    }
  };

  short8 sA[8], sB[8], sC[8];
  float nhA, nhB, nhC;
  stage(sA, nhA, 0);
  stage(sB, nhB, 1);

  // rotate 3 buffers over tiles 0..14; tail proc(15). Depth-2 prefetch.
  for (int t = 0; t < 15; t += 3) {
    stage(sC, nhC, t + 2);
    __builtin_amdgcn_sched_barrier(0);        // pin load issue before MFMAs
    proc(sA, nhA, t);
    stage(sA, nhA, (t + 3 > 15) ? 15 : t + 3);
    __builtin_amdgcn_sched_barrier(0);
    proc(sB, nhB, t + 1);
    stage(sB, nhB, (t + 4 > 15) ? 15 : t + 4);
    __builtin_amdgcn_sched_barrier(0);
    proc(sC, nhC, t + 2);
  }
  proc(sA, nhA, 15);

  // fold across the 16 code-columns (lanes sharing q)
  #pragma unroll
  for (int off = 1; off < 16; off <<= 1) {
    #pragma unroll
    for (int i = 0; i < 8; ++i) {
      float ov = __shfl_xor(bestv[i], off, 64);
      int   oi = __shfl_xor(besti[i], off, 64);
      if (ov > bestv[i] || (ov == bestv[i] && oi < besti[i])) {
        bestv[i] = ov; besti[i] = oi;         // first-max (lowest idx) ties
      }
    }
  }
  if (c == 0) {
    #pragma unroll
    for (int t = 0; t < 2; ++t)
      #pragma unroll
      for (int r = 0; r < 4; ++r) {
        unsigned u = __float_as_uint(bestv[t * 4 + r]);
        unsigned su = (u & 0x80000000u) ? ~u : (u | 0x80000000u);
        keys[w][t * 16 + q * 4 + r] =
            ((unsigned long long)su << 32) |
            (unsigned long long)(0xFFFFFFFFu - (unsigned)besti[t * 4 + r]);
      }
  }
  __syncthreads();
  if (tid < 32) {                             // merge 4 code-quarters
    unsigned long long k0 = keys[0][tid], k1 = keys[1][tid];
    unsigned long long k2 = keys[2][tid], k3 = keys[3][tid];
    unsigned long long k = k0 > k1 ? k0 : k1;
    if (k2 > k) k = k2;
    if (k3 > k) k = k3;
    int code = (int)(0xFFFFFFFFu - (unsigned)(k & 0xFFFFFFFFull));
    out_ind[blockIdx.x * 32 + tid] = (float)code;
    scodes[tid] = code;
  }
  __syncthreads();
  // fused quantize write: 32 rows x 32 float4 = 1024 float4, 4 per thread
  #pragma unroll
  for (int it = 0; it < 4; ++it) {
    int idx = tid + it * 256;
    int row = idx >> 5, c4 = idx & 31;
    int code = scodes[row];
    *(float4*)(out_q + (size_t)(blockIdx.x * 32 + row) * DDIM + c4 * 4) =
        *(const float4*)(embed + (size_t)code * DDIM + c4 * 4);
  }
}

// ---- K3: fully-fused per-code finalize. Block c: scan out_ind (128 KB,
// L2-broadcast across blocks) -> LDS row list -> gather-sum x -> EMA ->
// out_ncs / out_nea / out_ne. Replaces scan_fin + scatter_rows + esum_fin
// (no buckets, no cursors, no histogram, 2 fewer launches). ----
#define LCAP 4096
__global__ __launch_bounds__(256) void esum_fin(
    const float* __restrict__ out_ind, const float* __restrict__ x,
    const float* __restrict__ cs, const float* __restrict__ ea,
    const float* __restrict__ cssum,
    float* __restrict__ out_ncs, float* __restrict__ out_nea,
    float* __restrict__ out_ne) {
  __shared__ int list[LCAP];
  __shared__ int lcnt;
  __shared__ float4 part[512];
  const int code = blockIdx.x;
  const int t = threadIdx.x;
  const int c8 = t & 15;
  const int h = t >> 4;
  if (t == 0) lcnt = 0;
  __syncthreads();
  // phase 1: coalesced scan of out_ind, collect matching rows
  #pragma unroll 4
  for (int i = 0; i < 128; ++i) {
    int row = i * 256 + t;
    if ((int)out_ind[row] == code) {
      int p = atomicAdd(&lcnt, 1);
      if (p < LCAP) list[p] = row;
    }
  }
  __syncthreads();
  const int cnt = lcnt;
  float4 a0 = {0.f, 0.f, 0.f, 0.f}, a1 = {0.f, 0.f, 0.f, 0.f};
  if (cnt <= LCAP) {
    int i = h;
    for (; i + 16 < cnt; i += 32) {
      int rowA = list[i];
      int rowB = list[i + 16];
      const float* pa = x + (size_t)rowA * DDIM + c8 * 8;
      const float* pb = x + (size_t)rowB * DDIM + c8 * 8;
      float4 xa0 = *(const float4*)(pa), xa1 = *(const float4*)(pa + 4);
      float4 xb0 = *(const float4*)(pb), xb1 = *(const float4*)(pb + 4);
      a0.x += xa0.x + xb0.x; a0.y += xa0.y + xb0.y; a0.z += xa0.z + xb0.z; a0.w += xa0.w + xb0.w;
      a1.x += xa1.x + xb1.x; a1.y += xa1.y + xb1.y; a1.z += xa1.z + xb1.z; a1.w += xa1.w + xb1.w;
    }
    for (; i < cnt; i += 16) {
      int row = list[i];
      const float* pa = x + (size_t)row * DDIM + c8 * 8;
      float4 xa0 = *(const float4*)(pa), xa1 = *(const float4*)(pa + 4);
      a0.x += xa0.x; a0.y += xa0.y; a0.z += xa0.z; a0.w += xa0.w;
      a1.x += xa1.x; a1.y += xa1.y; a1.z += xa1.z; a1.w += xa1.w;
    }
  } else {
    // overflow fallback (adversarial inputs only): direct strided rescan
    for (int row = h; row < NROWS; row += 16) {
      if ((int)out_ind[row] == code) {
        const float* pa = x + (size_t)row * DDIM + c8 * 8;
        float4 xa0 = *(const float4*)(pa), xa1 = *(const float4*)(pa + 4);
        a0.x += xa0.x; a0.y += xa0.y; a0.z += xa0.z; a0.w += xa0.w;
        a1.x += xa1.x; a1.y += xa1.y; a1.z += xa1.z; a1.w += xa1.w;
      }
    }
  }
  part[h * 32 + c8 * 2]     = a0;
  part[h * 32 + c8 * 2 + 1] = a1;
  __syncthreads();
  if (t < 32) {
    float4 s = part[t];
    #pragma unroll
    for (int hh = 1; hh < 16; ++hh) {
      float4 p = part[hh * 32 + t];
      s.x += p.x; s.y += p.y; s.z += p.z; s.w += p.w;
    }
    const float ncs = cs[code] * DECAY + OMD * (float)cnt;
    const float total = cssum[0] * DECAY + OMD * (float)NROWS;
    const float iv = (total + (float)KCODES * EPS) / ((ncs + EPS) * total);
    if (t == 0) out_ncs[code] = ncs;
    int base = code * DDIM + t * 4;
    float4 a = *(const float4*)(ea + base);
    float4 nea;
    nea.x = a.x * DECAY + OMD * s.x; nea.y = a.y * DECAY + OMD * s.y;
    nea.z = a.z * DECAY + OMD * s.z; nea.w = a.w * DECAY + OMD * s.w;
    *(float4*)(out_nea + base) = nea;
    float4 ne;
    ne.x = nea.x * iv; ne.y = nea.y * iv; ne.z = nea.z * iv; ne.w = nea.w * iv;
    *(float4*)(out_ne + base) = ne;
  }
}

extern "C" void kernel_launch(void* const* d_in, const int* in_sizes, int n_in,
                              void* d_out, int out_size, void* d_ws, size_t ws_size,
                              hipStream_t stream) {
  const float* x     = (const float*)d_in[0];
  const float* embed = (const float*)d_in[1];
  const float* cs    = (const float*)d_in[2];
  const float* ea    = (const float*)d_in[3];

  float* out     = (float*)d_out;
  float* out_q   = out;                       // 4194304
  float* out_ind = out_q + 4194304;           // 32768
  float* out_ncs = out_ind + 32768;           // 1024
  float* out_nea = out_ncs + 1024;            // 131072
  float* out_ne  = out_nea + 131072;          // 131072

  float* ws     = (float*)d_ws;
  float* cssum  = ws + WS_CSSUM;
  float* en2h   = ws + WS_EN2H;

  // epack scratch aliased into out_nea (512 KB); read only by vq_mfma,
  // overwritten later by esum_fin.
  ushort* epack = (ushort*)out_nea;

  pack_e<<<16, 256, 0, stream>>>(embed, epack, en2h, cs, cssum);
  vq_mfma<<<NROWS / 32, 256, 0, stream>>>(x, (const short8*)epack, en2h, embed,
                                          out_ind, out_q);
  esum_fin<<<KCODES, 256, 0, stream>>>(out_ind, x, cs, ea, cssum,
                                       out_ncs, out_nea, out_ne);
}